// Round 1
// baseline (451.332 us; speedup 1.0000x reference)
//
#include <hip/hip_runtime.h>
#include <hip/hip_bf16.h>
#include <stdint.h>

#define DM 1024   // d_model
#define DD 512    // d (head dim / proj out)
#define BB 32     // batch
#define LL 1024   // seq len
#define SCALE 0.04419417382415922f  // 1/sqrt(512)

typedef float f32x4 __attribute__((ext_vector_type(4)));
typedef short bf16x8 __attribute__((ext_vector_type(8)));
typedef short bf16x4 __attribute__((ext_vector_type(4)));

__device__ inline unsigned short f2bf(float f) {
    union { float f; uint32_t u; } v; v.f = f;
    uint32_t r = v.u + 0x7fffu + ((v.u >> 16) & 1u);
    return (unsigned short)(r >> 16);
}

__device__ inline bf16x4 cvt4(f32x4 a, float s) {
    bf16x4 r;
    r[0] = (short)f2bf(a[0] * s);
    r[1] = (short)f2bf(a[1] * s);
    r[2] = (short)f2bf(a[2] * s);
    r[3] = (short)f2bf(a[3] * s);
    return r;
}

// ---------------------------------------------------------------------------
// Kernel 1: q/k/v projection.  C[m][n] = sum_k x[m][k] * W[n][k] + b[n]
// bf16 MFMA, 128x128 tile, BK=32, 4 waves (each wave 64x64 = 4x4 frags).
// fp32 inputs converted to bf16 during LDS staging; q scaled by 1/sqrt(D).
// Output bf16 row-major into ws.
// ---------------------------------------------------------------------------
__global__ __launch_bounds__(256) void qkv_proj(
    const float* __restrict__ x,
    const float* __restrict__ Wq, const float* __restrict__ bq,
    const float* __restrict__ Wk, const float* __restrict__ bk,
    const float* __restrict__ Wv, const float* __restrict__ bv,
    unsigned short* __restrict__ qkv)
{
    __shared__ __align__(16) unsigned short At[128][40];  // row stride 80B: 16B-aligned, 2-way banks
    __shared__ __align__(16) unsigned short Bt[128][40];

    const int o = blockIdx.y;  // 0=q 1=k 2=v
    const float* W    = (o == 0) ? Wq : (o == 1) ? Wk : Wv;
    const float* bias = (o == 0) ? bq : (o == 1) ? bk : bv;
    const float wscale = (o == 0) ? SCALE : 1.0f;
    unsigned short* out = qkv + (size_t)o * (size_t)(BB * LL) * DD;

    // XCD-aware swizzle over the 1024 x-blocks (1024 = 8 * 128, bijective)
    int wg = blockIdx.x;
    wg = (wg & 7) * 128 + (wg >> 3);
    const int rowbase = (wg >> 2) * 128;
    const int colbase = (wg & 3) * 128;

    const int tid  = threadIdx.x;
    const int lane = tid & 63;
    const int w    = tid >> 6;
    const int wr   = (w >> 1) * 64;
    const int wc   = (w & 1) * 64;

    f32x4 acc[4][4];
    #pragma unroll
    for (int i = 0; i < 4; ++i)
        #pragma unroll
        for (int j = 0; j < 4; ++j)
            acc[i][j] = (f32x4){0.f, 0.f, 0.f, 0.f};

    for (int kk = 0; kk < DM; kk += 32) {
        const float* xs = x + (size_t)rowbase * DM + kk;
        const float* wp = W + (size_t)colbase * DM + kk;
        #pragma unroll
        for (int i = 0; i < 4; ++i) {
            int c = tid + i * 256;        // 1024 float4-chunks: 128 rows x 8
            int r = c >> 3;
            int f = (c & 7) * 4;
            f32x4 xv = *(const f32x4*)(xs + (size_t)r * DM + f);
            *(bf16x4*)&At[r][f] = cvt4(xv, 1.0f);
            f32x4 wv = *(const f32x4*)(wp + (size_t)r * DM + f);
            *(bf16x4*)&Bt[r][f] = cvt4(wv, wscale);
        }
        __syncthreads();

        bf16x8 af[4], bfr[4];
        #pragma unroll
        for (int m = 0; m < 4; ++m)
            af[m] = *(const bf16x8*)&At[wr + m * 16 + (lane & 15)][(lane >> 4) * 8];
        #pragma unroll
        for (int n = 0; n < 4; ++n)
            bfr[n] = *(const bf16x8*)&Bt[wc + n * 16 + (lane & 15)][(lane >> 4) * 8];
        #pragma unroll
        for (int n = 0; n < 4; ++n)
            #pragma unroll
            for (int m = 0; m < 4; ++m)
                acc[m][n] = __builtin_amdgcn_mfma_f32_16x16x32_bf16(af[m], bfr[n], acc[m][n], 0, 0, 0);
        __syncthreads();
    }

    // epilogue: + bias (q-scaled), cvt bf16, store
    #pragma unroll
    for (int n = 0; n < 4; ++n) {
        int col = colbase + wc + n * 16 + (lane & 15);
        float bv_ = bias[col] * wscale;
        #pragma unroll
        for (int m = 0; m < 4; ++m) {
            int row0 = rowbase + wr + m * 16 + (lane >> 4) * 4;
            #pragma unroll
            for (int r = 0; r < 4; ++r)
                out[(size_t)(row0 + r) * DD + col] = f2bf(acc[m][n][r] + bv_);
        }
    }
}

// ---------------------------------------------------------------------------
// Kernel 2: flash attention, causal + padding mask, relu epilogue.
// Block = (batch b, q-tile of 64 rows). 512 threads = 8 waves.
// Wave w: wm = w>>2 (row half), wd = w&3 (128-wide d/n slice).
// QK^T: each wave computes partial S[wm*32..+32][0..32] over its 128-d slice,
// reduced through LDS. Online softmax: 8 lanes per row. PV: wave owns
// O[wm*32..+32][wd*128..+128].
// ---------------------------------------------------------------------------
__global__ __launch_bounds__(512) void attn(
    const unsigned short* __restrict__ qkv,
    const int* __restrict__ mask,
    float* __restrict__ outp)
{
    __shared__ __align__(16) unsigned short Kt[32][520];   // 33,280 B
    __shared__ __align__(16) unsigned short Vt[512][40];   // 40,960 B (V transposed: [d][key])
    __shared__ float Spart[8][32][33];                     // 33,792 B
    __shared__ __align__(16) unsigned short P[64][40];     //  5,120 B
    __shared__ float mrun[64], lrun[64], corrS[64];

    const int qt   = blockIdx.x;   // 0..15
    const int b    = blockIdx.y;   // 0..31
    const int tid  = threadIdx.x;
    const int lane = tid & 63;
    const int w    = tid >> 6;
    const int wm   = w >> 2;   // 0..1
    const int wd   = w & 3;    // 0..3

    const unsigned short* q = qkv;
    const unsigned short* k = qkv + (size_t)(BB * LL) * DD;
    const unsigned short* v = k   + (size_t)(BB * LL) * DD;

    // Q fragments (held in registers for the whole kernel)
    bf16x8 qf[2][4];
    {
        const unsigned short* qb = q + (size_t)(b * LL + qt * 64 + wm * 32) * DD;
        #pragma unroll
        for (int mf = 0; mf < 2; ++mf)
            #pragma unroll
            for (int kf = 0; kf < 4; ++kf)
                qf[mf][kf] = *(const bf16x8*)(qb + (size_t)(mf * 16 + (lane & 15)) * DD
                                                 + wd * 128 + kf * 32 + (lane >> 4) * 8);
    }

    f32x4 oacc[2][8];
    #pragma unroll
    for (int mf = 0; mf < 2; ++mf)
        #pragma unroll
        for (int nf = 0; nf < 8; ++nf)
            oacc[mf][nf] = (f32x4){0.f, 0.f, 0.f, 0.f};

    if (tid < 64) { mrun[tid] = -3e38f; lrun[tid] = 0.f; }

    const int jtmax = 2 * qt + 1;
    for (int jt = 0; jt <= jtmax; ++jt) {
        const int j0 = jt * 32;
        __syncthreads();  // prior-iter LDS reads done (and init visible on iter 0)

        // ---- stage K tile (row-major) and V tile (transposed) ----
        #pragma unroll
        for (int i = 0; i < 4; ++i) {
            int c   = tid + i * 512;          // 2048 chunks = 32 keys x 64 d-chunks
            int key = c >> 6;
            int d0  = (c & 63) * 8;
            const unsigned short* kp = k + (size_t)(b * LL + j0 + key) * DD + d0;
            *(bf16x8*)&Kt[key][d0] = *(const bf16x8*)kp;
            const unsigned short* vp = v + (size_t)(b * LL + j0 + key) * DD + d0;
            bf16x8 vv8 = *(const bf16x8*)vp;
            #pragma unroll
            for (int e0 = 0; e0 < 8; ++e0) {
                int e = (e0 + lane) & 7;      // rotate to spread banks (8-way instead of 64-way)
                Vt[d0 + e][key] = vv8[e];
            }
        }
        __syncthreads();

        // ---- QK^T partial over this wave's 128-wide d slice ----
        f32x4 sacc[2][2];
        #pragma unroll
        for (int mf = 0; mf < 2; ++mf)
            #pragma unroll
            for (int nf = 0; nf < 2; ++nf)
                sacc[mf][nf] = (f32x4){0.f, 0.f, 0.f, 0.f};
        #pragma unroll
        for (int nf = 0; nf < 2; ++nf) {
            #pragma unroll
            for (int kf = 0; kf < 4; ++kf) {
                bf16x8 kfrag = *(const bf16x8*)&Kt[nf * 16 + (lane & 15)]
                                               [wd * 128 + kf * 32 + (lane >> 4) * 8];
                #pragma unroll
                for (int mf = 0; mf < 2; ++mf)
                    sacc[mf][nf] = __builtin_amdgcn_mfma_f32_16x16x32_bf16(
                        qf[mf][kf], kfrag, sacc[mf][nf], 0, 0, 0);
            }
        }
        #pragma unroll
        for (int mf = 0; mf < 2; ++mf)
            #pragma unroll
            for (int nf = 0; nf < 2; ++nf)
                #pragma unroll
                for (int r = 0; r < 4; ++r)
                    Spart[w][mf * 16 + (lane >> 4) * 4 + r][nf * 16 + (lane & 15)] = sacc[mf][nf][r];
        __syncthreads();

        // ---- reduce partials + mask + online softmax (8 lanes per row) ----
        {
            int row  = tid >> 3;
            int sc   = tid & 7;
            int gi   = qt * 64 + row;
            int base = (row >> 5) * 4;
            int r32  = row & 31;
            float s[4];
            #pragma unroll
            for (int c4 = 0; c4 < 4; ++c4) {
                int col = sc + c4 * 8;
                float ss = Spart[base + 0][r32][col] + Spart[base + 1][r32][col]
                         + Spart[base + 2][r32][col] + Spart[base + 3][r32][col];
                int gj = j0 + col;
                bool ok = (gj <= gi) && (mask[b * LL + gj] != 0);
                s[c4] = ok ? ss : -1e30f;
            }
            float mx = fmaxf(fmaxf(s[0], s[1]), fmaxf(s[2], s[3]));
            mx = fmaxf(mx, __shfl_xor(mx, 1));
            mx = fmaxf(mx, __shfl_xor(mx, 2));
            mx = fmaxf(mx, __shfl_xor(mx, 4));
            float mold = mrun[row];
            float mnew = fmaxf(mold, mx);
            float corr = __expf(mold - mnew);
            float ls = 0.f;
            #pragma unroll
            for (int c4 = 0; c4 < 4; ++c4) {
                float p = __expf(s[c4] - mnew);
                ls += p;
                P[row][sc + c4 * 8] = f2bf(p);
            }
            ls += __shfl_xor(ls, 1);
            ls += __shfl_xor(ls, 2);
            ls += __shfl_xor(ls, 4);
            if (sc == 0) {
                mrun[row]  = mnew;
                lrun[row]  = lrun[row] * corr + ls;
                corrS[row] = corr;
            }
        }
        __syncthreads();

        // ---- rescale O, then PV ----
        float cr[2][4];
        #pragma unroll
        for (int mf = 0; mf < 2; ++mf)
            #pragma unroll
            for (int r = 0; r < 4; ++r)
                cr[mf][r] = corrS[wm * 32 + mf * 16 + (lane >> 4) * 4 + r];
        #pragma unroll
        for (int mf = 0; mf < 2; ++mf)
            #pragma unroll
            for (int nf = 0; nf < 8; ++nf)
                #pragma unroll
                for (int r = 0; r < 4; ++r)
                    oacc[mf][nf][r] *= cr[mf][r];

        bf16x8 pa[2];
        #pragma unroll
        for (int mf = 0; mf < 2; ++mf)
            pa[mf] = *(const bf16x8*)&P[wm * 32 + mf * 16 + (lane & 15)][(lane >> 4) * 8];
        #pragma unroll
        for (int nf = 0; nf < 8; ++nf) {
            bf16x8 vb = *(const bf16x8*)&Vt[wd * 128 + nf * 16 + (lane & 15)][(lane >> 4) * 8];
            #pragma unroll
            for (int mf = 0; mf < 2; ++mf)
                oacc[mf][nf] = __builtin_amdgcn_mfma_f32_16x16x32_bf16(pa[mf], vb, oacc[mf][nf], 0, 0, 0);
        }
    }

    // ---- epilogue: relu(O / l) ----
    #pragma unroll
    for (int mf = 0; mf < 2; ++mf) {
        #pragma unroll
        for (int r = 0; r < 4; ++r) {
            int rloc = wm * 32 + mf * 16 + (lane >> 4) * 4 + r;
            int row  = qt * 64 + rloc;
            float li = 1.0f / lrun[rloc];
            float* op = outp + (size_t)(b * LL + row) * DD + wd * 128 + (lane & 15);
            #pragma unroll
            for (int nf = 0; nf < 8; ++nf) {
                float val = oacc[mf][nf][r] * li;
                op[nf * 16] = fmaxf(val, 0.f);
            }
        }
    }
}

extern "C" void kernel_launch(void* const* d_in, const int* in_sizes, int n_in,
                              void* d_out, int out_size, void* d_ws, size_t ws_size,
                              hipStream_t stream) {
    const float* x  = (const float*)d_in[0];
    const float* Wq = (const float*)d_in[1];
    const float* bq = (const float*)d_in[2];
    const float* Wk = (const float*)d_in[3];
    const float* bk = (const float*)d_in[4];
    const float* Wv = (const float*)d_in[5];
    const float* bv = (const float*)d_in[6];
    const int* mask = (const int*)d_in[7];
    unsigned short* qkv = (unsigned short*)d_ws;  // q | k | v, each [B*L][D] bf16
    float* out = (float*)d_out;

    qkv_proj<<<dim3(1024, 3), 256, 0, stream>>>(x, Wq, bq, Wk, bk, Wv, bv, qkv);
    attn<<<dim3(16, 32), 512, 0, stream>>>(qkv, mask, out);
}